// Round 1
// baseline (1754.239 us; speedup 1.0000x reference)
//
#include <hip/hip_runtime.h>
#include <hip/hip_bf16.h>
#include <math.h>

#define NBATCH 64
#define TSEQ   1000
#define DIN    257
#define HID    128
#define GATES  512   // 4*HID

typedef _Float16 h2    __attribute__((ext_vector_type(2)));
typedef _Float16 h4    __attribute__((ext_vector_type(4)));
typedef _Float16 half8 __attribute__((ext_vector_type(8)));
typedef float    f32x4 __attribute__((ext_vector_type(4)));

__device__ __forceinline__ float fast_sigmoid(float x) {
    return __builtin_amdgcn_rcpf(1.f + __expf(-x));
}
__device__ __forceinline__ float fast_tanh(float x) {
    const float ax = fabsf(x);
    const float e  = __expf(2.f * ax);
    const float t  = 1.f - 2.f * __builtin_amdgcn_rcpf(e + 1.f);
    return copysignf(t, x);
}
// sum over aligned groups of 4 lanes (quad): xor1 then xor2 via quad_perm DPP
__device__ __forceinline__ float dpp_red4(float x) {
    int v = __builtin_bit_cast(int, x);
    int y = __builtin_amdgcn_update_dpp(0, v, 0xB1, 0xF, 0xF, true); // [1,0,3,2]
    x += __builtin_bit_cast(float, y);
    v = __builtin_bit_cast(int, x);
    y = __builtin_amdgcn_update_dpp(0, v, 0x4E, 0xF, 0xF, true);     // [2,3,0,1]
    return x + __builtin_bit_cast(float, y);
}

// ---------------------------------------------------------------------------
// f16 MFMA GEMM: C[M,Ncols] = act(A[M,K] @ W[Ncols,K]^T + b1 (+b2)), fp32 I/O.
// (unchanged from previous round — GEMMs are ~360us of 1457us; lstm_rec is
// the bottleneck this round.)
// ---------------------------------------------------------------------------
#define BM 128
#define BN 64
#define BK 64
#define LDK 88

template<int ACT>
__global__ __launch_bounds__(256) void gemm_mfma(
    const float* __restrict__ A, const float* __restrict__ W,
    const float* __restrict__ b1, const float* __restrict__ b2,
    float* __restrict__ C, int M, int K, int Ncols)
{
    __shared__ _Float16 As[BM][LDK];
    __shared__ _Float16 Ws[BN][LDK];

    const int tid  = threadIdx.x;
    const int wave = tid >> 6;
    const int lane = tid & 63;
    const int r    = lane & 15;
    const int q    = lane >> 4;
    const int m0   = blockIdx.y * BM;
    const int n0   = blockIdx.x * BN;
    const int wm   = (wave >> 1) * 64;
    const int wn   = (wave & 1) * 32;

    const int r16 = tid >> 4;        // staging row sub-index 0..15
    const int c4  = (tid & 15) * 4;  // staging k-offset (floats)

    f32x4 acc[4][2];
#pragma unroll
    for (int i = 0; i < 4; ++i)
#pragma unroll
        for (int j = 0; j < 2; ++j) acc[i][j] = f32x4{0.f, 0.f, 0.f, 0.f};

    for (int kc = 0; kc < K; kc += BK) {
        const int kg = kc + c4;
        const bool vec_ok = (kg + 4 <= K);   // uniform within 16-lane row group

        // ---- stage A: 128 rows; 8 iters of 16 rows, contiguous per row
#pragma unroll
        for (int it = 0; it < 8; ++it) {
            const int row = it * 16 + r16;
            const float* src = A + (size_t)(m0 + row) * K + kg;
            _Float16 tmp[4];
            if (vec_ok) {
                const float4 u = *(const float4*)src;
                tmp[0] = (_Float16)u.x; tmp[1] = (_Float16)u.y;
                tmp[2] = (_Float16)u.z; tmp[3] = (_Float16)u.w;
            } else {
#pragma unroll
                for (int j = 0; j < 4; ++j)
                    tmp[j] = (kg + j < K) ? (_Float16)src[j] : (_Float16)0.f;
            }
            *(h4*)&As[row][c4] = *(h4*)tmp;
        }
        // ---- stage W: 64 rows; 4 iters of 16 rows
#pragma unroll
        for (int it = 0; it < 4; ++it) {
            const int row  = it * 16 + r16;
            const int wrow = n0 + row;
            _Float16 tmp[4] = {(_Float16)0.f, (_Float16)0.f, (_Float16)0.f, (_Float16)0.f};
            if (wrow < Ncols) {
                const float* src = W + (size_t)wrow * K + kg;
                if (vec_ok) {
                    const float4 u = *(const float4*)src;
                    tmp[0] = (_Float16)u.x; tmp[1] = (_Float16)u.y;
                    tmp[2] = (_Float16)u.z; tmp[3] = (_Float16)u.w;
                } else {
#pragma unroll
                    for (int j = 0; j < 4; ++j)
                        tmp[j] = (kg + j < K) ? (_Float16)src[j] : (_Float16)0.f;
                }
            }
            *(h4*)&Ws[row][c4] = *(h4*)tmp;
        }
        __syncthreads();

        // ---- MFMA: two 32-k sub-chunks per buffer
#pragma unroll
        for (int s = 0; s < 2; ++s) {
            const int kb = s * 32 + q * 8;
            half8 af[4], wf[2];
#pragma unroll
            for (int i = 0; i < 4; ++i)
                af[i] = *(const half8*)&As[wm + i * 16 + r][kb];
#pragma unroll
            for (int j = 0; j < 2; ++j)
                wf[j] = *(const half8*)&Ws[wn + j * 16 + r][kb];
#pragma unroll
            for (int i = 0; i < 4; ++i)
#pragma unroll
                for (int j = 0; j < 2; ++j)
                    acc[i][j] = __builtin_amdgcn_mfma_f32_16x16x32_f16(
                        af[i], wf[j], acc[i][j], 0, 0, 0);
        }
        __syncthreads();
    }

    // ---- epilogue: row=(lane>>4)*4+reg, col=lane&15
#pragma unroll
    for (int i = 0; i < 4; ++i) {
#pragma unroll
        for (int j = 0; j < 2; ++j) {
            const int col = n0 + wn + j * 16 + r;
            if (col < Ncols) {
                const float bias = b1[col] + (b2 ? b2[col] : 0.f);
#pragma unroll
                for (int reg = 0; reg < 4; ++reg) {
                    const int row = m0 + wm + i * 16 + q * 4 + reg;
                    float v = acc[i][j][reg] + bias;
                    if (ACT == 1) v = fast_sigmoid(v);
                    C[(size_t)row * Ncols + col] = v;
                }
            }
        }
    }
}

// ---------------------------------------------------------------------------
// LSTM recurrence. R7 change: K split 4-ways (kh=tid&3, 32 K-elems/thread)
// instead of 2-ways. 512 threads/block -> 8 waves -> 2 waves/SIMD.
// Rationale (counters): step latency was 1316 cyc vs ~370 cyc issue floor at
// 1 wave/SIMD; the serial 128-fdot2 issue chain (256 cyc) plus exposed LDS/
// dep-chain latency dominated. Halving the per-wave fdot2 chain (64 fdot2 =
// 128 cyc issue, 4 ds_read_b128) and co-scheduling a second wave per SIMD
// fills the stalls. Reduce is now a 2-stage DPP quad reduce. Whh slice per
// thread halves to 64 VGPRs -> ~95 VGPR total, fine at 2 waves/EU.
// ---------------------------------------------------------------------------
__global__ __launch_bounds__(512, 2) void lstm_rec(
    const float* __restrict__ pre, const float* __restrict__ states_in,
    const float* __restrict__ Whh, float* __restrict__ hseq,
    float* __restrict__ states_out, int h_row0)
{
    const int n   = blockIdx.x;
    const int tid = threadIdx.x;
    const int j   = tid >> 2;   // output index 0..127
    const int kh  = tid & 3;    // K-quarter 0..3 (32 elems each)

    // register-resident Whh slice: 4 gate rows x 32 K-cols (as 16 h2)
    h2 w[4][16];
#pragma unroll
    for (int a = 0; a < 4; ++a) {
        const float2* rr = (const float2*)(Whh + (size_t)(j + a * HID) * HID + kh * 32);
#pragma unroll
        for (int m = 0; m < 16; ++m) {
            const float2 v = rr[m];
            w[a][m] = h2{(_Float16)v.x, (_Float16)v.y};
        }
    }

    __shared__ __align__(16) unsigned short hbuf[2][HID];

    float c_r = states_in[(size_t)(h_row0 + 64 + n) * HID + j];
    if (tid < HID) {
        const float h0 = states_in[(size_t)(h_row0 + n) * HID + tid];
        hbuf[0][tid] = __builtin_bit_cast(unsigned short, (_Float16)h0);
    }
    __syncthreads();

    const float* pre_n = pre + (size_t)n * TSEQ * GATES;
    float p0c = pre_n[j],            p1c = pre_n[j + 128];
    float p2c = pre_n[j + 256],      p3c = pre_n[j + 384];
    float p0n = pre_n[GATES + j],        p1n = pre_n[GATES + j + 128];
    float p2n = pre_n[GATES + j + 256],  p3n = pre_n[GATES + j + 384];

    int cur = 0;
    for (int t = 0; t < TSEQ; ++t) {
        const float p0 = p0c, p1 = p1c, p2 = p2c, p3 = p3c;
        p0c = p0n; p1c = p1n; p2c = p2n; p3c = p3n;
        if (t + 2 < TSEQ) {
            const float* pn = pre_n + (size_t)(t + 2) * GATES;
            p0n = pn[j];       p1n = pn[j + 128];
            p2n = pn[j + 256]; p3n = pn[j + 384];
        }

        const uint4* hb = (const uint4*)&hbuf[cur][0];
        float a0 = 0.f, a1 = 0.f, a2 = 0.f, a3 = 0.f;
#pragma unroll
        for (int c = 0; c < 4; ++c) {
            const uint4 hv = hb[kh * 4 + c];
            const h2 q0 = __builtin_bit_cast(h2, hv.x);
            const h2 q1 = __builtin_bit_cast(h2, hv.y);
            const h2 q2 = __builtin_bit_cast(h2, hv.z);
            const h2 q3 = __builtin_bit_cast(h2, hv.w);
            a0 = __builtin_amdgcn_fdot2(w[0][4 * c + 0], q0, a0, false);
            a1 = __builtin_amdgcn_fdot2(w[1][4 * c + 0], q0, a1, false);
            a2 = __builtin_amdgcn_fdot2(w[2][4 * c + 0], q0, a2, false);
            a3 = __builtin_amdgcn_fdot2(w[3][4 * c + 0], q0, a3, false);
            a0 = __builtin_amdgcn_fdot2(w[0][4 * c + 1], q1, a0, false);
            a1 = __builtin_amdgcn_fdot2(w[1][4 * c + 1], q1, a1, false);
            a2 = __builtin_amdgcn_fdot2(w[2][4 * c + 1], q1, a2, false);
            a3 = __builtin_amdgcn_fdot2(w[3][4 * c + 1], q1, a3, false);
            a0 = __builtin_amdgcn_fdot2(w[0][4 * c + 2], q2, a0, false);
            a1 = __builtin_amdgcn_fdot2(w[1][4 * c + 2], q2, a1, false);
            a2 = __builtin_amdgcn_fdot2(w[2][4 * c + 2], q2, a2, false);
            a3 = __builtin_amdgcn_fdot2(w[3][4 * c + 2], q2, a3, false);
            a0 = __builtin_amdgcn_fdot2(w[0][4 * c + 3], q3, a0, false);
            a1 = __builtin_amdgcn_fdot2(w[1][4 * c + 3], q3, a1, false);
            a2 = __builtin_amdgcn_fdot2(w[2][4 * c + 3], q3, a2, false);
            a3 = __builtin_amdgcn_fdot2(w[3][4 * c + 3], q3, a3, false);
        }

        // full gate pre-activations: reduce over the 4 kh lanes of this j
        const float gi = fast_sigmoid(dpp_red4(a0) + p0);
        const float gf = fast_sigmoid(dpp_red4(a1) + p1);
        const float gg = fast_tanh   (dpp_red4(a2) + p2);
        const float go = fast_sigmoid(dpp_red4(a3) + p3);

        const float cn = gf * c_r + gi * gg;
        const float hh = go * fast_tanh(cn);
        c_r = cn;

        if (kh == 1) {
            hbuf[cur ^ 1][j] = __builtin_bit_cast(unsigned short, (_Float16)hh);
        } else if (kh == 0) {
            hseq[((size_t)n * TSEQ + t) * HID + j] = hh;
            if (t == TSEQ - 1) {
                states_out[(size_t)(h_row0 + n) * HID + j]      = hh;
                states_out[(size_t)(h_row0 + 64 + n) * HID + j] = cn;
            }
        }
        __syncthreads();
        cur ^= 1;
    }
}

// ---------------------------------------------------------------------------
extern "C" void kernel_launch(void* const* d_in, const int* in_sizes, int n_in,
                              void* d_out, int out_size, void* d_ws, size_t ws_size,
                              hipStream_t stream)
{
    const float* x     = (const float*)d_in[0];
    const float* st_in = (const float*)d_in[1];
    const float* Wih1  = (const float*)d_in[2];
    const float* Whh1  = (const float*)d_in[3];
    const float* bih1  = (const float*)d_in[4];
    const float* bhh1  = (const float*)d_in[5];
    const float* Wih2  = (const float*)d_in[6];
    const float* Whh2  = (const float*)d_in[7];
    const float* bih2  = (const float*)d_in[8];
    const float* bhh2  = (const float*)d_in[9];
    const float* Wd    = (const float*)d_in[10];
    const float* bd    = (const float*)d_in[11];

    float* out_mask   = (float*)d_out;
    float* out_states = (float*)d_out + (size_t)NBATCH * TSEQ * DIN;

    const int M = NBATCH * TSEQ;
    float* bufA = (float*)d_ws;               // [M,512] pre1 / pre2
    float* bufB = bufA + (size_t)M * GATES;   // [M,128] h1seq / x2

    // K1: pre1 = x @ Wih1^T + bih1 + bhh1   (M=64000, K=257, N=512)
    gemm_mfma<0><<<dim3(GATES / BN, M / BM), 256, 0, stream>>>(
        x, Wih1, bih1, bhh1, bufA, M, DIN, GATES);

    lstm_rec<<<NBATCH, 512, 0, stream>>>(bufA, st_in, Whh1, bufB, out_states, 0);

    // K3: pre2 = h1seq @ Wih2^T + bih2 + bhh2   (K=128)
    gemm_mfma<0><<<dim3(GATES / BN, M / BM), 256, 0, stream>>>(
        bufB, Wih2, bih2, bhh2, bufA, M, HID, GATES);

    lstm_rec<<<NBATCH, 512, 0, stream>>>(bufA, st_in, Whh2, bufB, out_states, 128);

    // K5: mask = sigmoid(x2 @ Wd^T + bd)   (N=257)
    gemm_mfma<1><<<dim3((DIN + BN - 1) / BN, M / BM), 256, 0, stream>>>(
        bufB, Wd, bd, nullptr, out_mask, M, HID, DIN);
}

// Round 2
// 1479.112 us; speedup vs baseline: 1.1860x; 1.1860x over previous
//
#include <hip/hip_runtime.h>
#include <hip/hip_bf16.h>
#include <math.h>

#define NBATCH 64
#define TSEQ   1000
#define DIN    257
#define HID    128
#define GATES  512   // 4*HID

typedef _Float16 h2    __attribute__((ext_vector_type(2)));
typedef _Float16 h4    __attribute__((ext_vector_type(4)));
typedef _Float16 half8 __attribute__((ext_vector_type(8)));
typedef float    f32x4 __attribute__((ext_vector_type(4)));

__device__ __forceinline__ float fast_sigmoid(float x) {
    return __builtin_amdgcn_rcpf(1.f + __expf(-x));
}
// branchless tanh: tanh(x) = 1 - 2/(exp(2x)+1), exact identity, valid all x
// (exp overflow -> inf -> rcp -> 0 -> +1; underflow -> 0 -> -1)
__device__ __forceinline__ float fast_tanh(float x) {
    const float e = __expf(2.f * x);
    return 1.f - 2.f * __builtin_amdgcn_rcpf(e + 1.f);
}

// ---------------------------------------------------------------------------
// f16 MFMA GEMM: C[M,Ncols] = act(A[M,K] @ W[Ncols,K]^T + b1 (+b2)), fp32 I/O.
// (unchanged — GEMMs are ~360us; lstm_rec is the bottleneck.)
// ---------------------------------------------------------------------------
#define BM 128
#define BN 64
#define BK 64
#define LDK 88

template<int ACT>
__global__ __launch_bounds__(256) void gemm_mfma(
    const float* __restrict__ A, const float* __restrict__ W,
    const float* __restrict__ b1, const float* __restrict__ b2,
    float* __restrict__ C, int M, int K, int Ncols)
{
    __shared__ _Float16 As[BM][LDK];
    __shared__ _Float16 Ws[BN][LDK];

    const int tid  = threadIdx.x;
    const int wave = tid >> 6;
    const int lane = tid & 63;
    const int r    = lane & 15;
    const int q    = lane >> 4;
    const int m0   = blockIdx.y * BM;
    const int n0   = blockIdx.x * BN;
    const int wm   = (wave >> 1) * 64;
    const int wn   = (wave & 1) * 32;

    const int r16 = tid >> 4;        // staging row sub-index 0..15
    const int c4  = (tid & 15) * 4;  // staging k-offset (floats)

    f32x4 acc[4][2];
#pragma unroll
    for (int i = 0; i < 4; ++i)
#pragma unroll
        for (int j = 0; j < 2; ++j) acc[i][j] = f32x4{0.f, 0.f, 0.f, 0.f};

    for (int kc = 0; kc < K; kc += BK) {
        const int kg = kc + c4;
        const bool vec_ok = (kg + 4 <= K);   // uniform within 16-lane row group

        // ---- stage A: 128 rows; 8 iters of 16 rows, contiguous per row
#pragma unroll
        for (int it = 0; it < 8; ++it) {
            const int row = it * 16 + r16;
            const float* src = A + (size_t)(m0 + row) * K + kg;
            _Float16 tmp[4];
            if (vec_ok) {
                const float4 u = *(const float4*)src;
                tmp[0] = (_Float16)u.x; tmp[1] = (_Float16)u.y;
                tmp[2] = (_Float16)u.z; tmp[3] = (_Float16)u.w;
            } else {
#pragma unroll
                for (int j = 0; j < 4; ++j)
                    tmp[j] = (kg + j < K) ? (_Float16)src[j] : (_Float16)0.f;
            }
            *(h4*)&As[row][c4] = *(h4*)tmp;
        }
        // ---- stage W: 64 rows; 4 iters of 16 rows
#pragma unroll
        for (int it = 0; it < 4; ++it) {
            const int row  = it * 16 + r16;
            const int wrow = n0 + row;
            _Float16 tmp[4] = {(_Float16)0.f, (_Float16)0.f, (_Float16)0.f, (_Float16)0.f};
            if (wrow < Ncols) {
                const float* src = W + (size_t)wrow * K + kg;
                if (vec_ok) {
                    const float4 u = *(const float4*)src;
                    tmp[0] = (_Float16)u.x; tmp[1] = (_Float16)u.y;
                    tmp[2] = (_Float16)u.z; tmp[3] = (_Float16)u.w;
                } else {
#pragma unroll
                    for (int j = 0; j < 4; ++j)
                        tmp[j] = (kg + j < K) ? (_Float16)src[j] : (_Float16)0.f;
                }
            }
            *(h4*)&Ws[row][c4] = *(h4*)tmp;
        }
        __syncthreads();

        // ---- MFMA: two 32-k sub-chunks per buffer
#pragma unroll
        for (int s = 0; s < 2; ++s) {
            const int kb = s * 32 + q * 8;
            half8 af[4], wf[2];
#pragma unroll
            for (int i = 0; i < 4; ++i)
                af[i] = *(const half8*)&As[wm + i * 16 + r][kb];
#pragma unroll
            for (int j = 0; j < 2; ++j)
                wf[j] = *(const half8*)&Ws[wn + j * 16 + r][kb];
#pragma unroll
            for (int i = 0; i < 4; ++i)
#pragma unroll
                for (int j = 0; j < 2; ++j)
                    acc[i][j] = __builtin_amdgcn_mfma_f32_16x16x32_f16(
                        af[i], wf[j], acc[i][j], 0, 0, 0);
        }
        __syncthreads();
    }

    // ---- epilogue: row=(lane>>4)*4+reg, col=lane&15
#pragma unroll
    for (int i = 0; i < 4; ++i) {
#pragma unroll
        for (int j = 0; j < 2; ++j) {
            const int col = n0 + wn + j * 16 + r;
            if (col < Ncols) {
                const float bias = b1[col] + (b2 ? b2[col] : 0.f);
#pragma unroll
                for (int reg = 0; reg < 4; ++reg) {
                    const int row = m0 + wm + i * 16 + q * 4 + reg;
                    float v = acc[i][j][reg] + bias;
                    if (ACT == 1) v = fast_sigmoid(v);
                    C[(size_t)row * Ncols + col] = v;
                }
            }
        }
    }
}

// ---------------------------------------------------------------------------
// LSTM recurrence, R2: MFMA matvec (h replicated in A-rows, Whh rows in
// register-resident B-frags). Post-mortem of R1: waves are phase-locked by
// the per-step barrier, so extra waves only add issue contention. This
// version moves the 256-cyc fdot2 chain to the matrix pipe (32 MFMA/wave
// ~155 cyc), removes the DPP k-reduce entirely (MFMA reduces K internally),
// and keeps gate math at 1 j per lane (no duplication).
// Layouts mirror the proven GEMM above:
//   A-frag: lane holds A[m=lane&15][k=q*8+e]  -> h[k] (r-independent = LDS
//           broadcast read)
//   B-frag: lane holds W[row=16ct+r][k=q*8+e] -> Whh rows, regs (loaded once)
//   D:      col=lane&15 -> Whh row; rows replicated (A rows identical)
// Wave w owns gate rows {128g + 32w + 16b2 + r}; lane uses b2 == (q&1), so
// each lane holds all 4 gates of j = 32w + 16(q&1) + r. q-pair redundancy
// splits the tail: q<2 lanes write h to LDS, q>=2 lanes store hseq.
// ---------------------------------------------------------------------------
__global__ __launch_bounds__(256, 1) void lstm_rec(
    const float* __restrict__ pre, const float* __restrict__ states_in,
    const float* __restrict__ Whh, float* __restrict__ hseq,
    float* __restrict__ states_out, int h_row0)
{
    const int n    = blockIdx.x;
    const int tid  = threadIdx.x;
    const int w    = tid >> 6;
    const int lane = tid & 63;
    const int r    = lane & 15;
    const int q    = lane >> 4;
    const int b    = q & 1;
    const int j    = 32 * w + 16 * b + r;   // this lane's output index

    // Whh fragments: wf[g][b2][s], row = 128g + 32w + 16*b2 + r, k = s*32+q*8..+7
    // 4*2*4 half8 = 128 VGPR of weights, loaded once.
    half8 wf[4][2][4];
#pragma unroll
    for (int g = 0; g < 4; ++g) {
#pragma unroll
        for (int b2 = 0; b2 < 2; ++b2) {
            const float* src = Whh + (size_t)(128 * g + 32 * w + 16 * b2 + r) * HID + q * 8;
#pragma unroll
            for (int s = 0; s < 4; ++s) {
                const float4 u0 = *(const float4*)(src + s * 32);
                const float4 u1 = *(const float4*)(src + s * 32 + 4);
                half8 tf;
                tf[0] = (_Float16)u0.x; tf[1] = (_Float16)u0.y;
                tf[2] = (_Float16)u0.z; tf[3] = (_Float16)u0.w;
                tf[4] = (_Float16)u1.x; tf[5] = (_Float16)u1.y;
                tf[6] = (_Float16)u1.z; tf[7] = (_Float16)u1.w;
                wf[g][b2][s] = tf;
            }
        }
    }

    __shared__ __align__(16) _Float16 hbuf[2][HID];

    float c_r = states_in[(size_t)(h_row0 + 64 + n) * HID + j];
    if (tid < HID)
        hbuf[0][tid] = (_Float16)states_in[(size_t)(h_row0 + n) * HID + tid];
    __syncthreads();

    const float* pre_n = pre + (size_t)n * TSEQ * GATES;
    float pc0 = pre_n[j],           pc1 = pre_n[j + 128];
    float pc2 = pre_n[j + 256],     pc3 = pre_n[j + 384];
    float pn0 = pre_n[GATES + j],       pn1 = pre_n[GATES + j + 128];
    float pn2 = pre_n[GATES + j + 256], pn3 = pre_n[GATES + j + 384];

    int cur = 0;
    for (int t = 0; t < TSEQ; ++t) {
        const float p0 = pc0, p1 = pc1, p2 = pc2, p3 = pc3;
        pc0 = pn0; pc1 = pn1; pc2 = pn2; pc3 = pn3;
        if (t + 2 < TSEQ) {
            const float* pp = pre_n + (size_t)(t + 2) * GATES + j;
            pn0 = pp[0]; pn1 = pp[128]; pn2 = pp[256]; pn3 = pp[384];
        }

        // h fragments: broadcast reads (same 16B within each 16-lane group)
        half8 hx[4];
#pragma unroll
        for (int s = 0; s < 4; ++s)
            hx[s] = *(const half8*)&hbuf[cur][s * 32 + q * 8];

        // init acc with p (C operand of MFMA adds elementwise per lane;
        // only element-of-own-b2 frag is consumed, rest harmless finite)
        f32x4 acc[4][2];
        acc[0][0] = f32x4{p0, p0, p0, p0}; acc[0][1] = f32x4{p0, p0, p0, p0};
        acc[1][0] = f32x4{p1, p1, p1, p1}; acc[1][1] = f32x4{p1, p1, p1, p1};
        acc[2][0] = f32x4{p2, p2, p2, p2}; acc[2][1] = f32x4{p2, p2, p2, p2};
        acc[3][0] = f32x4{p3, p3, p3, p3}; acc[3][1] = f32x4{p3, p3, p3, p3};

#pragma unroll
        for (int s = 0; s < 4; ++s) {
#pragma unroll
            for (int g = 0; g < 4; ++g) {
#pragma unroll
                for (int b2 = 0; b2 < 2; ++b2)
                    acc[g][b2] = __builtin_amdgcn_mfma_f32_16x16x32_f16(
                        hx[s], wf[g][b2][s], acc[g][b2], 0, 0, 0);
            }
        }

        // static selection of own-b2 fragment (no runtime array index)
        const float A0 = b ? acc[0][1][0] : acc[0][0][0];
        const float A1 = b ? acc[1][1][0] : acc[1][0][0];
        const float A2 = b ? acc[2][1][0] : acc[2][0][0];
        const float A3 = b ? acc[3][1][0] : acc[3][0][0];

        const float gi = fast_sigmoid(A0);
        const float gf = fast_sigmoid(A1);
        const float gg = fast_tanh(A2);
        const float go = fast_sigmoid(A3);

        const float cn = gf * c_r + gi * gg;
        const float hh = go * fast_tanh(cn);
        c_r = cn;

        if (q < 2) {
            hbuf[cur ^ 1][j] = (_Float16)hh;
            if (t == TSEQ - 1)
                states_out[(size_t)(h_row0 + 64 + n) * HID + j] = cn;
        } else {
            hseq[((size_t)n * TSEQ + t) * HID + j] = hh;
            if (t == TSEQ - 1)
                states_out[(size_t)(h_row0 + n) * HID + j] = hh;
        }
        __syncthreads();
        cur ^= 1;
    }
}

// ---------------------------------------------------------------------------
extern "C" void kernel_launch(void* const* d_in, const int* in_sizes, int n_in,
                              void* d_out, int out_size, void* d_ws, size_t ws_size,
                              hipStream_t stream)
{
    const float* x     = (const float*)d_in[0];
    const float* st_in = (const float*)d_in[1];
    const float* Wih1  = (const float*)d_in[2];
    const float* Whh1  = (const float*)d_in[3];
    const float* bih1  = (const float*)d_in[4];
    const float* bhh1  = (const float*)d_in[5];
    const float* Wih2  = (const float*)d_in[6];
    const float* Whh2  = (const float*)d_in[7];
    const float* bih2  = (const float*)d_in[8];
    const float* bhh2  = (const float*)d_in[9];
    const float* Wd    = (const float*)d_in[10];
    const float* bd    = (const float*)d_in[11];

    float* out_mask   = (float*)d_out;
    float* out_states = (float*)d_out + (size_t)NBATCH * TSEQ * DIN;

    const int M = NBATCH * TSEQ;
    float* bufA = (float*)d_ws;               // [M,512] pre1 / pre2
    float* bufB = bufA + (size_t)M * GATES;   // [M,128] h1seq / x2

    // K1: pre1 = x @ Wih1^T + bih1 + bhh1   (M=64000, K=257, N=512)
    gemm_mfma<0><<<dim3(GATES / BN, M / BM), 256, 0, stream>>>(
        x, Wih1, bih1, bhh1, bufA, M, DIN, GATES);

    lstm_rec<<<NBATCH, 256, 0, stream>>>(bufA, st_in, Whh1, bufB, out_states, 0);

    // K3: pre2 = h1seq @ Wih2^T + bih2 + bhh2   (K=128)
    gemm_mfma<0><<<dim3(GATES / BN, M / BM), 256, 0, stream>>>(
        bufB, Wih2, bih2, bhh2, bufA, M, HID, GATES);

    lstm_rec<<<NBATCH, 256, 0, stream>>>(bufA, st_in, Whh2, bufB, out_states, 128);

    // K5: mask = sigmoid(x2 @ Wd^T + bd)   (N=257)
    gemm_mfma<1><<<dim3((DIN + BN - 1) / BN, M / BM), 256, 0, stream>>>(
        bufB, Wd, bd, nullptr, out_mask, M, HID, DIN);
}

// Round 3
// 1266.542 us; speedup vs baseline: 1.3851x; 1.1678x over previous
//
#include <hip/hip_runtime.h>
#include <hip/hip_bf16.h>
#include <math.h>

#define NBATCH 64
#define TSEQ   1000
#define DIN    257
#define HID    128
#define GATES  512   // 4*HID
#define CH     8     // pipeline chunk (timesteps)
#define NCHUNK 125   // TSEQ / CH

typedef _Float16 h2    __attribute__((ext_vector_type(2)));
typedef _Float16 h4    __attribute__((ext_vector_type(4)));
typedef _Float16 half8 __attribute__((ext_vector_type(8)));
typedef float    f32x4 __attribute__((ext_vector_type(4)));

__device__ __forceinline__ float fast_sigmoid(float x) {
    return __builtin_amdgcn_rcpf(1.f + __expf(-x));
}
// branchless tanh: tanh(x) = 1 - 2/(exp(2x)+1), exact identity, valid all x
__device__ __forceinline__ float fast_tanh(float x) {
    const float e = __expf(2.f * x);
    return 1.f - 2.f * __builtin_amdgcn_rcpf(e + 1.f);
}
__device__ __forceinline__ void wait_flag(const int* f, int need) {
    while (__hip_atomic_load(f, __ATOMIC_ACQUIRE, __HIP_MEMORY_SCOPE_AGENT) < need)
        __builtin_amdgcn_s_sleep(2);
}

// ---------------------------------------------------------------------------
// f16 MFMA GEMM (unchanged): C = act(A @ W^T + b1 (+b2)), fp32 I/O.
// Used for pre1 (K=257) and the final mask GEMM.
// ---------------------------------------------------------------------------
#define BM 128
#define BN 64
#define BK 64
#define LDK 88

template<int ACT>
__global__ __launch_bounds__(256) void gemm_mfma(
    const float* __restrict__ A, const float* __restrict__ W,
    const float* __restrict__ b1, const float* __restrict__ b2,
    float* __restrict__ C, int M, int K, int Ncols)
{
    __shared__ _Float16 As[BM][LDK];
    __shared__ _Float16 Ws[BN][LDK];

    const int tid  = threadIdx.x;
    const int wave = tid >> 6;
    const int lane = tid & 63;
    const int r    = lane & 15;
    const int q    = lane >> 4;
    const int m0   = blockIdx.y * BM;
    const int n0   = blockIdx.x * BN;
    const int wm   = (wave >> 1) * 64;
    const int wn   = (wave & 1) * 32;

    const int r16 = tid >> 4;
    const int c4  = (tid & 15) * 4;

    f32x4 acc[4][2];
#pragma unroll
    for (int i = 0; i < 4; ++i)
#pragma unroll
        for (int j = 0; j < 2; ++j) acc[i][j] = f32x4{0.f, 0.f, 0.f, 0.f};

    for (int kc = 0; kc < K; kc += BK) {
        const int kg = kc + c4;
        const bool vec_ok = (kg + 4 <= K);

#pragma unroll
        for (int it = 0; it < 8; ++it) {
            const int row = it * 16 + r16;
            const float* src = A + (size_t)(m0 + row) * K + kg;
            _Float16 tmp[4];
            if (vec_ok) {
                const float4 u = *(const float4*)src;
                tmp[0] = (_Float16)u.x; tmp[1] = (_Float16)u.y;
                tmp[2] = (_Float16)u.z; tmp[3] = (_Float16)u.w;
            } else {
#pragma unroll
                for (int j = 0; j < 4; ++j)
                    tmp[j] = (kg + j < K) ? (_Float16)src[j] : (_Float16)0.f;
            }
            *(h4*)&As[row][c4] = *(h4*)tmp;
        }
#pragma unroll
        for (int it = 0; it < 4; ++it) {
            const int row  = it * 16 + r16;
            const int wrow = n0 + row;
            _Float16 tmp[4] = {(_Float16)0.f, (_Float16)0.f, (_Float16)0.f, (_Float16)0.f};
            if (wrow < Ncols) {
                const float* src = W + (size_t)wrow * K + kg;
                if (vec_ok) {
                    const float4 u = *(const float4*)src;
                    tmp[0] = (_Float16)u.x; tmp[1] = (_Float16)u.y;
                    tmp[2] = (_Float16)u.z; tmp[3] = (_Float16)u.w;
                } else {
#pragma unroll
                    for (int j = 0; j < 4; ++j)
                        tmp[j] = (kg + j < K) ? (_Float16)src[j] : (_Float16)0.f;
                }
            }
            *(h4*)&Ws[row][c4] = *(h4*)tmp;
        }
        __syncthreads();

#pragma unroll
        for (int s = 0; s < 2; ++s) {
            const int kb = s * 32 + q * 8;
            half8 af[4], wfr[2];
#pragma unroll
            for (int i = 0; i < 4; ++i)
                af[i] = *(const half8*)&As[wm + i * 16 + r][kb];
#pragma unroll
            for (int j = 0; j < 2; ++j)
                wfr[j] = *(const half8*)&Ws[wn + j * 16 + r][kb];
#pragma unroll
            for (int i = 0; i < 4; ++i)
#pragma unroll
                for (int j = 0; j < 2; ++j)
                    acc[i][j] = __builtin_amdgcn_mfma_f32_16x16x32_f16(
                        af[i], wfr[j], acc[i][j], 0, 0, 0);
        }
        __syncthreads();
    }

#pragma unroll
    for (int i = 0; i < 4; ++i) {
#pragma unroll
        for (int j = 0; j < 2; ++j) {
            const int col = n0 + wn + j * 16 + r;
            if (col < Ncols) {
                const float bias = b1[col] + (b2 ? b2[col] : 0.f);
#pragma unroll
                for (int reg = 0; reg < 4; ++reg) {
                    const int row = m0 + wm + i * 16 + q * 4 + reg;
                    float v = acc[i][j][reg] + bias;
                    if (ACT == 1) v = fast_sigmoid(v);
                    C[(size_t)row * Ncols + col] = v;
                }
            }
        }
    }
}

// ---------------------------------------------------------------------------
// R3: fused pipelined recurrence (replaces K2 + K3 + K4).
// 128 blocks: blocks 0-63 = layer-1 chain n; blocks 64-127 = layer-2 chain n.
//
// Layer-1 block: R2's MFMA recurrence, PLUS per-8-step chunk it computes
// pre2 = h1_chunk @ Wih2^T + bias itself (h1 chunk kept in LDS f16; Wih2
// register-resident; 32 extra MFMA/wave/chunk ~= +78 cyc/step) and writes it
// in-place over pre1 (row t written only after row t+2 consumed -> safe).
// Flag release: flags[n] = c published at END of chunk c's steps, covering
// chunks 0..c-1 (their stores drained by the >=8 intervening per-step
// __syncthreads vmcnt(0) drains); threadfence = agent release (L2 wb) makes
// them cross-XCD visible.  h1seq is never written to global (saves traffic).
//
// Layer-2 block: R2's recurrence reading pre2, gated at each chunk start on
// flags[n] >= c+2 (prefetch t+2 reaches row 8c+9 < 8(c+2)). Steady-state lag
// ~3 chunks (~25 us fill).  Deadlock-free: 128 blocks, 1/CU, all co-resident.
//
// Rec micro-opt vs R2: first MFMA takes C=0 (one shared zero quad instead of
// 32 p-broadcast movs/step); p added at readout.
// ---------------------------------------------------------------------------
__global__ __launch_bounds__(256, 1) void lstm_mega(
    float* preA,                       // pre1 (read, L1) / pre2 (written L1, read L2)
    const float* __restrict__ states_in,
    const float* __restrict__ Whh1, const float* __restrict__ Whh2,
    const float* __restrict__ Wih2, const float* __restrict__ bih2,
    const float* __restrict__ bhh2,
    float* __restrict__ h2seq,         // bufB: layer-2 hidden sequence (for mask GEMM)
    float* __restrict__ states_out, int* __restrict__ flags)
{
    const int layer = blockIdx.x >> 6;
    const int n     = blockIdx.x & 63;
    const int tid   = threadIdx.x;
    const int w     = tid >> 6;
    const int lane  = tid & 63;
    const int r     = lane & 15;
    const int q     = lane >> 4;
    const int b     = q & 1;
    const int j     = 32 * w + 16 * b + r;   // this lane's output index
    const int h_row0 = layer ? 128 : 0;

    __shared__ __align__(16) _Float16 hbuf[2][HID];
    __shared__ __align__(16) _Float16 h1ck[2][CH][136];  // padded: bank-spread A-frags

    // ---- recurrence weights (both layers): wf[g][b2][s], row=128g+32w+16b2+r
    const float* Whh = layer ? Whh2 : Whh1;
    half8 wf[4][2][4];
#pragma unroll
    for (int g = 0; g < 4; ++g) {
#pragma unroll
        for (int b2 = 0; b2 < 2; ++b2) {
            const float* src = Whh + (size_t)(128 * g + 32 * w + 16 * b2 + r) * HID + q * 8;
#pragma unroll
            for (int s = 0; s < 4; ++s) {
                const float4 u0 = *(const float4*)(src + s * 32);
                const float4 u1 = *(const float4*)(src + s * 32 + 4);
                half8 tf;
                tf[0] = (_Float16)u0.x; tf[1] = (_Float16)u0.y;
                tf[2] = (_Float16)u0.z; tf[3] = (_Float16)u0.w;
                tf[4] = (_Float16)u1.x; tf[5] = (_Float16)u1.y;
                tf[6] = (_Float16)u1.z; tf[7] = (_Float16)u1.w;
                wf[g][b2][s] = tf;
            }
        }
    }

    // ---- layer-1 extra: Wih2 B-frags (wave w owns pre2 cols 128w..128w+127)
    half8 wih[8][4];
    float bias2v[8];
    if (layer == 0) {
#pragma unroll
        for (int fi = 0; fi < 8; ++fi) {
            const int row = 128 * w + 16 * fi + r;
            const float* src = Wih2 + (size_t)row * HID + q * 8;
#pragma unroll
            for (int s = 0; s < 4; ++s) {
                const float4 u0 = *(const float4*)(src + s * 32);
                const float4 u1 = *(const float4*)(src + s * 32 + 4);
                half8 tf;
                tf[0] = (_Float16)u0.x; tf[1] = (_Float16)u0.y;
                tf[2] = (_Float16)u0.z; tf[3] = (_Float16)u0.w;
                tf[4] = (_Float16)u1.x; tf[5] = (_Float16)u1.y;
                tf[6] = (_Float16)u1.z; tf[7] = (_Float16)u1.w;
                wih[fi][s] = tf;
            }
            bias2v[fi] = bih2[row] + bhh2[row];
        }
    }

    float c_r = states_in[(size_t)(h_row0 + 64 + n) * HID + j];
    if (tid < HID)
        hbuf[0][tid] = (_Float16)states_in[(size_t)(h_row0 + n) * HID + tid];
    __syncthreads();

    // layer-2: gate the initial prefetch (rows 0,1)
    if (layer) wait_flag(flags + n, 2);

    const float* pre_n = preA + (size_t)n * TSEQ * GATES;
    float pc0 = pre_n[j],           pc1 = pre_n[j + 128];
    float pc2 = pre_n[j + 256],     pc3 = pre_n[j + 384];
    float pn0 = pre_n[GATES + j],       pn1 = pre_n[GATES + j + 128];
    float pn2 = pre_n[GATES + j + 256], pn3 = pre_n[GATES + j + 384];

    int cur = 0;
    for (int t = 0; t < TSEQ; ++t) {
        if (layer && t && !(t & 7)) {
            int need = (t >> 3) + 2;
            if (need > NCHUNK) need = NCHUNK;
            wait_flag(flags + n, need);
        }

        const float p0 = pc0, p1 = pc1, p2 = pc2, p3 = pc3;
        pc0 = pn0; pc1 = pn1; pc2 = pn2; pc3 = pn3;
        if (t + 2 < TSEQ) {
            const float* pp = pre_n + (size_t)(t + 2) * GATES + j;
            pn0 = pp[0]; pn1 = pp[128]; pn2 = pp[256]; pn3 = pp[384];
        }

        half8 hx[4];
#pragma unroll
        for (int s = 0; s < 4; ++s)
            hx[s] = *(const half8*)&hbuf[cur][s * 32 + q * 8];

        f32x4 acc[4][2];
        const f32x4 Z = {0.f, 0.f, 0.f, 0.f};
#pragma unroll
        for (int g = 0; g < 4; ++g)
#pragma unroll
            for (int b2 = 0; b2 < 2; ++b2)
                acc[g][b2] = __builtin_amdgcn_mfma_f32_16x16x32_f16(
                    hx[0], wf[g][b2][0], Z, 0, 0, 0);
#pragma unroll
        for (int s = 1; s < 4; ++s)
#pragma unroll
            for (int g = 0; g < 4; ++g)
#pragma unroll
                for (int b2 = 0; b2 < 2; ++b2)
                    acc[g][b2] = __builtin_amdgcn_mfma_f32_16x16x32_f16(
                        hx[s], wf[g][b2][s], acc[g][b2], 0, 0, 0);

        const float A0 = (b ? acc[0][1][0] : acc[0][0][0]) + p0;
        const float A1 = (b ? acc[1][1][0] : acc[1][0][0]) + p1;
        const float A2 = (b ? acc[2][1][0] : acc[2][0][0]) + p2;
        const float A3 = (b ? acc[3][1][0] : acc[3][0][0]) + p3;

        const float gi = fast_sigmoid(A0);
        const float gf = fast_sigmoid(A1);
        const float gg = fast_tanh(A2);
        const float go = fast_sigmoid(A3);

        const float cn = gf * c_r + gi * gg;
        const float hh = go * fast_tanh(cn);
        c_r = cn;

        if (q < 2) {
            hbuf[cur ^ 1][j] = (_Float16)hh;
            if (t == TSEQ - 1)
                states_out[(size_t)(h_row0 + 64 + n) * HID + j] = cn;
        } else {
            if (layer == 0)
                h1ck[(t >> 3) & 1][t & 7][j] = (_Float16)hh;
            else
                h2seq[((size_t)n * TSEQ + t) * HID + j] = hh;
            if (t == TSEQ - 1)
                states_out[(size_t)(h_row0 + n) * HID + j] = hh;
        }
        __syncthreads();

        // ---- layer-1 chunk tail: release previous chunks, GEMM this chunk
        if (layer == 0 && (t & 7) == 7) {
            const int c = t >> 3;
            if (c > 0 && tid == 0) {
                __threadfence();   // agent release: L2 writeback of pre2 chunks < c
                __hip_atomic_store(flags + n, c, __ATOMIC_RELAXED, __HIP_MEMORY_SCOPE_AGENT);
            }
            const int cb = c & 1;
            // A-frag: m=r -> step (r&7; rows 8-15 replicas, unused in D)
            half8 ax[4];
#pragma unroll
            for (int s = 0; s < 4; ++s)
                ax[s] = *(const half8*)&h1ck[cb][r & 7][s * 32 + q * 8];
            f32x4 gacc[8];
            const f32x4 GZ = {0.f, 0.f, 0.f, 0.f};
#pragma unroll
            for (int fi = 0; fi < 8; ++fi)
                gacc[fi] = __builtin_amdgcn_mfma_f32_16x16x32_f16(
                    ax[0], wih[fi][0], GZ, 0, 0, 0);
#pragma unroll
            for (int s = 1; s < 4; ++s)
#pragma unroll
                for (int fi = 0; fi < 8; ++fi)
                    gacc[fi] = __builtin_amdgcn_mfma_f32_16x16x32_f16(
                        ax[s], wih[fi][s], gacc[fi], 0, 0, 0);
            // D: row=4q+reg=step, col=r -> pre2[(n, 8c+step)][128w+16fi+r]
            if (q < 2) {
                float* dst0 = preA + ((size_t)n * TSEQ + (t - 7 + 4 * q)) * GATES + 128 * w + r;
#pragma unroll
                for (int fi = 0; fi < 8; ++fi)
#pragma unroll
                    for (int reg = 0; reg < 4; ++reg)
                        dst0[(size_t)reg * GATES + 16 * fi] = gacc[fi][reg] + bias2v[fi];
            }
        }
        cur ^= 1;
    }

    if (layer == 0) {
        __syncthreads();           // drains final chunk's stores (vmcnt 0)
        if (tid == 0) {
            __threadfence();
            __hip_atomic_store(flags + n, NCHUNK, __ATOMIC_RELAXED, __HIP_MEMORY_SCOPE_AGENT);
        }
    }
}

// ---------------------------------------------------------------------------
extern "C" void kernel_launch(void* const* d_in, const int* in_sizes, int n_in,
                              void* d_out, int out_size, void* d_ws, size_t ws_size,
                              hipStream_t stream)
{
    const float* x     = (const float*)d_in[0];
    const float* st_in = (const float*)d_in[1];
    const float* Wih1  = (const float*)d_in[2];
    const float* Whh1  = (const float*)d_in[3];
    const float* bih1  = (const float*)d_in[4];
    const float* bhh1  = (const float*)d_in[5];
    const float* Wih2  = (const float*)d_in[6];
    const float* Whh2  = (const float*)d_in[7];
    const float* bih2  = (const float*)d_in[8];
    const float* bhh2  = (const float*)d_in[9];
    const float* Wd    = (const float*)d_in[10];
    const float* bd    = (const float*)d_in[11];

    float* out_mask   = (float*)d_out;
    float* out_states = (float*)d_out + (size_t)NBATCH * TSEQ * DIN;

    const int M = NBATCH * TSEQ;
    float* bufA = (float*)d_ws;               // [M,512] pre1, overwritten by pre2
    float* bufB = bufA + (size_t)M * GATES;   // [M,128] h2seq

    // flags: 64 ints in the tail of the mask region (overwritten later by K5,
    // which runs strictly after lstm_mega on this stream).
    int* flags = (int*)((float*)d_out + (size_t)NBATCH * TSEQ * DIN) - 64;
    hipMemsetAsync(flags, 0, 64 * sizeof(int), stream);

    // K1: pre1 = x @ Wih1^T + bih1 + bhh1   (M=64000, K=257, N=512)
    gemm_mfma<0><<<dim3(GATES / BN, M / BM), 256, 0, stream>>>(
        x, Wih1, bih1, bhh1, bufA, M, DIN, GATES);

    // fused pipelined L1 rec + pre2 + L2 rec
    lstm_mega<<<128, 256, 0, stream>>>(
        bufA, st_in, Whh1, Whh2, Wih2, bih2, bhh2, bufB, out_states, flags);

    // K5: mask = sigmoid(h2seq @ Wd^T + bd)   (N=257)
    gemm_mfma<1><<<dim3((DIN + BN - 1) / BN, M / BM), 256, 0, stream>>>(
        bufB, Wd, bd, nullptr, out_mask, M, HID, DIN);
}